// Round 3
// baseline (109.132 us; speedup 1.0000x reference)
//
#include <hip/hip_runtime.h>
#include <math.h>

namespace {
constexpr int NB = 2048;      // batch
constexpr int NNODE = 6;      // nodes
constexpr int DD = 2048;      // feature dim
constexpr int HH = 1024;      // hidden
constexpr int CC = 200;       // classes
constexpr int K2 = 2 * DD;    // 4096 (concat dim)
constexpr int NPAD = 256;     // padded class dim
constexpr int ZSPLIT = 8;     // split-K for gemm2
constexpr float ALPHA_C = 0.015f;
constexpr float SCALE_C = 24.0f;
}

typedef __attribute__((ext_vector_type(8))) short bf16x8;
typedef __attribute__((ext_vector_type(4))) float f32x4;

static __device__ __forceinline__ unsigned short f2bf(float x) {
    union { float f; unsigned int u; } v; v.f = x;
    unsigned int r = v.u + 0x7FFFu + ((v.u >> 16) & 1u);  // RNE
    return (unsigned short)(r >> 16);
}

// ---------------------------------------------------------------------------
// k_prep: blocks 0..63  -> cls_wT[256][1024] bf16 (transposed, zero-padded)
//         blocks 64..88 -> bvec[c] = fc_b @ cls_w + cls_b
// ---------------------------------------------------------------------------
__global__ __launch_bounds__(256) void k_prep(const float* __restrict__ cls_w,
                                              const float* __restrict__ fc_b,
                                              const float* __restrict__ cls_b,
                                              unsigned short* __restrict__ cls_wT,
                                              float* __restrict__ bvec)
{
    __shared__ float sm[64 * 65];
    const int x = blockIdx.x;
    const int t = threadIdx.x;
    if (x < 64) {
        const int kt = x & 15;   // k-tile (16 x 64 = 1024)
        const int nt = x >> 4;   // n-tile (4 x 64 = 256)
#pragma unroll
        for (int c = 0; c < 4; ++c) {
            int i = t + c * 256;
            int kr = i >> 4;
            int nc = (i & 15) << 2;
            int gn = nt * 64 + nc;
            const float* sp = cls_w + (size_t)(kt * 64 + kr) * CC + gn;
            float4 v = {0.f, 0.f, 0.f, 0.f};
            if (gn + 3 < CC) {
                v = *(const float4*)sp;
            } else {
                if (gn + 0 < CC) v.x = sp[0];
                if (gn + 1 < CC) v.y = sp[1];
                if (gn + 2 < CC) v.z = sp[2];
                if (gn + 3 < CC) v.w = sp[3];
            }
            sm[kr * 65 + nc + 0] = v.x; sm[kr * 65 + nc + 1] = v.y;
            sm[kr * 65 + nc + 2] = v.z; sm[kr * 65 + nc + 3] = v.w;
        }
        __syncthreads();
#pragma unroll
        for (int c = 0; c < 4; ++c) {
            int i = t + c * 256;
            int nr = i >> 4;
            int kc = (i & 15) << 2;
            ushort4 o;
            o.x = f2bf(sm[(kc + 0) * 65 + nr]);
            o.y = f2bf(sm[(kc + 1) * 65 + nr]);
            o.z = f2bf(sm[(kc + 2) * 65 + nr]);
            o.w = f2bf(sm[(kc + 3) * 65 + nr]);
            *(ushort4*)(cls_wT + (size_t)(nt * 64 + nr) * HH + kt * 64 + kc) = o;
        }
    } else {
        const int bb = x - 64;           // 0..24
        float* red = sm;
        int c8 = t & 7;
        int hs = t >> 3;
        int c = bb * 8 + c8;             // < 200
        float acc = 0.f;
        for (int h = hs; h < HH; h += 32)
            acc += fc_b[h] * cls_w[(size_t)h * CC + c];
        red[t] = acc;
        __syncthreads();
        for (int s = 128; s >= 8; s >>= 1) {
            if (t < s) red[t] += red[t + s];
            __syncthreads();
        }
        if (t < 8) bvec[c] = red[t] + cls_b[c];
    }
}

// ---------------------------------------------------------------------------
// GEMM1: Mt[256][4096] = (fc_w @ cls_w)^T, bf16 out. Reads fc_w as f32 and
// converts during LDS staging (no separate conversion pass).
// grid (64, 4); 64x64 tile; 4 waves of 32x32.
// ---------------------------------------------------------------------------
__global__ __launch_bounds__(256) void k_gemm1(const float* __restrict__ A,
                                               const unsigned short* __restrict__ Bt,
                                               unsigned short* __restrict__ Mt)
{
    __shared__ short As[64][72];   // +8 pad
    __shared__ short Bs[64][72];
    const int t = threadIdx.x;
    const int lane = t & 63;
    const int wid = t >> 6;
    const int wm = wid >> 1, wn = wid & 1;
    const int bm = blockIdx.x * 64, bn = blockIdx.y * 64;

    f32x4 acc[2][2] = {};

    for (int k0 = 0; k0 < HH; k0 += 64) {
        // A tile 64x64, f32 -> bf16 convert in flight
#pragma unroll
        for (int c = 0; c < 4; ++c) {
            int i = t + c * 256;
            int row = i >> 4;
            int nc = (i & 15) << 2;
            float4 v = *(const float4*)(A + (size_t)(bm + row) * HH + k0 + nc);
            ushort4 o;
            o.x = f2bf(v.x); o.y = f2bf(v.y); o.z = f2bf(v.z); o.w = f2bf(v.w);
            *(ushort4*)&As[row][nc] = o;
        }
        // B tile 64x64 bf16
#pragma unroll
        for (int c = 0; c < 2; ++c) {
            int i = t + c * 256;
            int row = i >> 3;
            int c8 = (i & 7) << 3;
            *(uint4*)&Bs[row][c8] =
                *(const uint4*)(Bt + (size_t)(bn + row) * HH + k0 + c8);
        }
        __syncthreads();
#pragma unroll
        for (int ks = 0; ks < 2; ++ks) {
            int kk = ks * 32 + ((lane >> 4) << 3);
            bf16x8 a0 = *(const bf16x8*)&As[wm * 32 + (lane & 15)][kk];
            bf16x8 a1 = *(const bf16x8*)&As[wm * 32 + 16 + (lane & 15)][kk];
            bf16x8 b0 = *(const bf16x8*)&Bs[wn * 32 + (lane & 15)][kk];
            bf16x8 b1 = *(const bf16x8*)&Bs[wn * 32 + 16 + (lane & 15)][kk];
            acc[0][0] = __builtin_amdgcn_mfma_f32_16x16x32_bf16(a0, b0, acc[0][0], 0, 0, 0);
            acc[0][1] = __builtin_amdgcn_mfma_f32_16x16x32_bf16(a0, b1, acc[0][1], 0, 0, 0);
            acc[1][0] = __builtin_amdgcn_mfma_f32_16x16x32_bf16(a1, b0, acc[1][0], 0, 0, 0);
            acc[1][1] = __builtin_amdgcn_mfma_f32_16x16x32_bf16(a1, b1, acc[1][1], 0, 0, 0);
        }
        __syncthreads();
    }
    // transposed store: Mt[n][m]
#pragma unroll
    for (int fm = 0; fm < 2; ++fm)
#pragma unroll
        for (int fn = 0; fn < 2; ++fn) {
            int gm0 = bm + wm * 32 + fm * 16 + ((lane >> 4) << 2);
            int gn = bn + wn * 32 + fn * 16 + (lane & 15);
            ushort4 o;
            o.x = f2bf(acc[fm][fn][0]); o.y = f2bf(acc[fm][fn][1]);
            o.z = f2bf(acc[fm][fn][2]); o.w = f2bf(acc[fm][fn][3]);
            *(ushort4*)(Mt + (size_t)gn * K2 + gm0) = o;
        }
}

// ---------------------------------------------------------------------------
// Fused s + pq: pq[b][0:D] = sum_u s[b,u]*pf[b,u,:], pq[b][D:2D] = sum_u pf
// Output bf16. grid = NB*2 blocks x 256 threads (4 floats/thread).
// ---------------------------------------------------------------------------
__global__ __launch_bounds__(256) void k_pq(const float* __restrict__ pf,
                                            const float* __restrict__ cdds,
                                            unsigned short* __restrict__ pq)
{
    int bid = blockIdx.x;
    int b = bid >> 1;
    int d = ((bid & 1) << 10) + (threadIdx.x << 2);

    const float* cd = cdds + (size_t)b * NNODE * 6;
    float cx[NNODE], cy[NNODE];
#pragma unroll
    for (int u = 0; u < NNODE; ++u) {
        cy[u] = (cd[u * 6 + 1] + cd[u * 6 + 3]) * 0.5f;
        cx[u] = (cd[u * 6 + 2] + cd[u * 6 + 4]) * 0.5f;
    }
    float w0[NNODE][NNODE];
    float sum = 0.f;
#pragma unroll
    for (int u = 0; u < NNODE; ++u)
#pragma unroll
        for (int v = 0; v < NNODE; ++v) {
            if (v == u) { w0[u][v] = 0.f; continue; }
            float dx = cx[u] - cx[v];
            float dy = cy[u] - cy[v];
            float w = expf(-ALPHA_C * sqrtf(dx * dx + dy * dy));
            w0[u][v] = w;
            sum += w;
        }
    float mean = sum * (1.f / 30.f);
    float sv[NNODE];
#pragma unroll
    for (int u = 0; u < NNODE; ++u) {
        float acc = 0.f;
#pragma unroll
        for (int v = 0; v < NNODE; ++v) {
            float tt = w0[u][v] - mean;
            if (v != u && tt > 0.f) acc += tt;
        }
        sv[u] = SCALE_C * acc * 0.2f;
    }

    const float* base = pf + (size_t)b * NNODE * DD + d;
    float4 p = {0.f, 0.f, 0.f, 0.f};
    float4 q = {0.f, 0.f, 0.f, 0.f};
#pragma unroll
    for (int u = 0; u < NNODE; ++u) {
        float4 a = *(const float4*)(base + (size_t)u * DD);
        p.x = fmaf(sv[u], a.x, p.x); p.y = fmaf(sv[u], a.y, p.y);
        p.z = fmaf(sv[u], a.z, p.z); p.w = fmaf(sv[u], a.w, p.w);
        q.x += a.x; q.y += a.y; q.z += a.z; q.w += a.w;
    }
    unsigned short* o = pq + (size_t)b * K2;
    ushort4 pb, qb;
    pb.x = f2bf(p.x); pb.y = f2bf(p.y); pb.z = f2bf(p.z); pb.w = f2bf(p.w);
    qb.x = f2bf(q.x); qb.y = f2bf(q.y); qb.z = f2bf(q.z); qb.w = f2bf(q.w);
    *(ushort4*)(o + d) = pb;
    *(ushort4*)(o + DD + d) = qb;
}

// ---------------------------------------------------------------------------
// GEMM2: part[z][2048][256] = pq[2048][4096] @ Mt^T  (bf16 MFMA, split-K=8)
// grid (16, 4, 8) = 512 blocks; 128x64 tile; 4 waves, each 32 rows x 64 cols
// (acc[2][4] -> better ds_read:MFMA ratio than 64x64).
// ---------------------------------------------------------------------------
__global__ __launch_bounds__(256) void k_gemm2(const unsigned short* __restrict__ A,
                                               const unsigned short* __restrict__ Bt,
                                               float* __restrict__ part)
{
    __shared__ short As[128][72];
    __shared__ short Bs[64][72];
    const int t = threadIdx.x;
    const int lane = t & 63;
    const int wid = t >> 6;
    const int bm = blockIdx.x * 128, bn = blockIdx.y * 64;
    const int z = blockIdx.z;
    const int kbase = z * (K2 / ZSPLIT);   // 512 per z

    f32x4 acc[2][4] = {};

    for (int k0 = kbase; k0 < kbase + K2 / ZSPLIT; k0 += 64) {
        // A tile 128x64
#pragma unroll
        for (int c = 0; c < 4; ++c) {
            int i = t + c * 256;
            int row = i >> 3;
            int c8 = (i & 7) << 3;
            *(uint4*)&As[row][c8] =
                *(const uint4*)(A + (size_t)(bm + row) * K2 + k0 + c8);
        }
        // B tile 64x64
#pragma unroll
        for (int c = 0; c < 2; ++c) {
            int i = t + c * 256;
            int row = i >> 3;
            int c8 = (i & 7) << 3;
            *(uint4*)&Bs[row][c8] =
                *(const uint4*)(Bt + (size_t)(bn + row) * K2 + k0 + c8);
        }
        __syncthreads();
#pragma unroll
        for (int ks = 0; ks < 2; ++ks) {
            int kk = ks * 32 + ((lane >> 4) << 3);
            bf16x8 a0 = *(const bf16x8*)&As[wid * 32 + (lane & 15)][kk];
            bf16x8 a1 = *(const bf16x8*)&As[wid * 32 + 16 + (lane & 15)][kk];
            bf16x8 bv0 = *(const bf16x8*)&Bs[0 * 16 + (lane & 15)][kk];
            bf16x8 bv1 = *(const bf16x8*)&Bs[1 * 16 + (lane & 15)][kk];
            bf16x8 bv2 = *(const bf16x8*)&Bs[2 * 16 + (lane & 15)][kk];
            bf16x8 bv3 = *(const bf16x8*)&Bs[3 * 16 + (lane & 15)][kk];
            acc[0][0] = __builtin_amdgcn_mfma_f32_16x16x32_bf16(a0, bv0, acc[0][0], 0, 0, 0);
            acc[1][0] = __builtin_amdgcn_mfma_f32_16x16x32_bf16(a1, bv0, acc[1][0], 0, 0, 0);
            acc[0][1] = __builtin_amdgcn_mfma_f32_16x16x32_bf16(a0, bv1, acc[0][1], 0, 0, 0);
            acc[1][1] = __builtin_amdgcn_mfma_f32_16x16x32_bf16(a1, bv1, acc[1][1], 0, 0, 0);
            acc[0][2] = __builtin_amdgcn_mfma_f32_16x16x32_bf16(a0, bv2, acc[0][2], 0, 0, 0);
            acc[1][2] = __builtin_amdgcn_mfma_f32_16x16x32_bf16(a1, bv2, acc[1][2], 0, 0, 0);
            acc[0][3] = __builtin_amdgcn_mfma_f32_16x16x32_bf16(a0, bv3, acc[0][3], 0, 0, 0);
            acc[1][3] = __builtin_amdgcn_mfma_f32_16x16x32_bf16(a1, bv3, acc[1][3], 0, 0, 0);
        }
        __syncthreads();
    }
#pragma unroll
    for (int fm = 0; fm < 2; ++fm)
#pragma unroll
        for (int fn = 0; fn < 4; ++fn) {
            int gm0 = bm + wid * 32 + fm * 16 + ((lane >> 4) << 2);
            int gn = bn + fn * 16 + (lane & 15);
#pragma unroll
            for (int r = 0; r < 4; ++r)
                part[((size_t)z * NB + gm0 + r) * NPAD + gn] = acc[fm][fn][r];
        }
}

// ---------------------------------------------------------------------------
// out[b,c] = (sum_z part[z][b][c]) / 6 + bvec[c]
// ---------------------------------------------------------------------------
__global__ __launch_bounds__(256) void k_combine(const float* __restrict__ part,
                                                 const float* __restrict__ bvec,
                                                 float* __restrict__ out)
{
    int idx = blockIdx.x * blockDim.x + threadIdx.x;
    if (idx >= NB * CC) return;
    int b = idx / CC;
    int c = idx - b * CC;
    float s = 0.f;
#pragma unroll
    for (int z = 0; z < ZSPLIT; ++z)
        s += part[((size_t)z * NB + b) * NPAD + c];
    out[idx] = s * (1.f / 6.f) + bvec[c];
}

// ---------------------------------------------------------------------------
extern "C" void kernel_launch(void* const* d_in, const int* in_sizes, int n_in,
                              void* d_out, int out_size, void* d_ws, size_t ws_size,
                              hipStream_t stream)
{
    const float* part_feats = (const float*)d_in[0];
    const float* cdds = (const float*)d_in[1];
    const float* fc_w = (const float*)d_in[2];   // (4096, 1024)
    const float* fc_b = (const float*)d_in[3];   // (1024,)
    const float* cls_w = (const float*)d_in[4];  // (1024, 200)
    const float* cls_b = (const float*)d_in[5];  // (200,)
    float* out = (float*)d_out;                  // (2048, 200)

    char* ws = (char*)d_ws;
    size_t off = 0;
    unsigned short* pq = (unsigned short*)(ws + off);     off += (size_t)NB * K2 * 2;           // 16.8 MB
    unsigned short* cls_wT = (unsigned short*)(ws + off); off += (size_t)NPAD * HH * 2;         // 0.5 MB
    unsigned short* Mt = (unsigned short*)(ws + off);     off += (size_t)NPAD * K2 * 2;         // 2.1 MB
    float* part = (float*)(ws + off);                     off += (size_t)ZSPLIT * NB * NPAD * 4;// 16.8 MB
    float* bvec = (float*)(ws + off);                     off += 256 * 4;

    // 1. cls_w transpose->bf16 + bias vector (one kernel, mixed blocks)
    k_prep<<<dim3(64 + 25), dim3(256), 0, stream>>>(cls_w, fc_b, cls_b, cls_wT, bvec);
    // 2. Mt = (fc_w @ cls_w)^T bf16 (reads fc_w f32, converts in staging)
    k_gemm1<<<dim3(K2 / 64, NPAD / 64), dim3(256), 0, stream>>>(fc_w, cls_wT, Mt);
    // 3. pq = [weighted-sum | sum] over nodes, bf16
    k_pq<<<dim3(NB * 2), dim3(256), 0, stream>>>(part_feats, cdds, pq);
    // 4. pq @ Mt^T partials, split-K=8
    k_gemm2<<<dim3(NB / 128, NPAD / 64, ZSPLIT), dim3(256), 0, stream>>>(pq, Mt, part);
    // 5. combine + scale + bias
    k_combine<<<dim3((NB * CC + 255) / 256), dim3(256), 0, stream>>>(part, bvec, out);
}